// Round 1
// baseline (661.867 us; speedup 1.0000x reference)
//
#include <hip/hip_runtime.h>

#define WARMUP  365
#define NSTEP   1825
#define TTOT    2190
#define KERNEL_ 15
#define CH      5      // chunk size: divides 365 and 1825

__global__ __launch_bounds__(64) void hbv_fused_kernel(
    const float* __restrict__ x,       // (TTOT, G, 3): precip, pet, temp
    const float* __restrict__ params,  // (G, 14) in [0,1]
    float* __restrict__ out,           // (NSTEP, G)
    int G)
{
    const int g = blockIdx.x * 64 + threadIdx.x;
    if (g >= G) return;

    // ---- scale parameters to physical ranges ----
    const float* pr = params + (size_t)g * 14;
    const float beta  = 1.0f   + pr[0]  * 5.0f;     // [1, 6]
    const float fc    = 50.0f  + pr[1]  * 950.0f;   // [50, 1000]
    const float k0    = 0.05f  + pr[2]  * 0.85f;    // [0.05, 0.9]
    const float k1    = 0.01f  + pr[3]  * 0.49f;    // [0.01, 0.5]
    const float k2    = 0.001f + pr[4]  * 0.199f;   // [0.001, 0.2]
    const float lp    = 0.2f   + pr[5]  * 0.8f;     // [0.2, 1]
    const float pperc =          pr[6]  * 10.0f;    // [0, 10]
    const float uzl   =          pr[7]  * 100.0f;   // [0, 100]
    const float tt    = -2.5f  + pr[8]  * 5.0f;     // [-2.5, 2.5]
    const float cfmax = 0.5f   + pr[9]  * 9.5f;     // [0.5, 10]
    const float cfr   =          pr[10] * 0.1f;     // [0, 0.1]
    const float cwh   =          pr[11] * 0.2f;     // [0, 0.2]
    const float ra    =          pr[12] * 2.9f;     // [0, 2.9]
    const float rb    =          pr[13] * 6.5f;     // [0, 6.5]

    // ---- unit hydrograph weights (gammaln + aa*log(theta) terms cancel
    //      under the sum-normalization, so they are omitted) ----
    const float aa = fmaxf(ra, 0.0f) + 0.1f;
    const float th = fmaxf(rb, 0.0f) + 0.5f;
    const float inv_th = 1.0f / th;
    float w[KERNEL_];
    float ws = 0.0f;
    #pragma unroll
    for (int k = 0; k < KERNEL_; k++) {
        const float tk = 0.5f + (float)k;
        const float lw = (aa - 1.0f) * __logf(tk) - tk * inv_th;
        w[k] = __expf(lw);
        ws += w[k];
    }
    const float inv_ws = 1.0f / ws;
    #pragma unroll
    for (int k = 0; k < KERNEL_; k++) w[k] *= inv_ws;

    // ---- precomputed reciprocals / products ----
    const float inv_fc   = 1.0f / fc;
    const float inv_lpfc = 1.0f / (lp * fc);
    const float cfrx     = cfr * cfmax;

    // ---- HBV state ----
    float sp  = 0.001f;  // snowpack
    float mw  = 0.001f;  // meltwater
    float sm  = 0.001f;  // soil moisture
    float suz = 0.001f;  // upper zone
    float slz = 0.001f;  // lower zone

    // One HBV step; returns discharge q
    auto step = [&](float precip, float pet, float temp) -> float {
        const float rain = (temp >= tt) ? precip : 0.0f;
        const float snow = precip - rain;
        sp += snow;
        const float melt = fminf(fmaxf(cfmax * (temp - tt), 0.0f), sp);
        mw += melt;
        sp -= melt;
        const float refr = fminf(fmaxf(cfrx * (tt - temp), 0.0f), mw);
        sp += refr;
        mw -= refr;
        const float tosoil = fmaxf(mw - cwh * sp, 0.0f);
        mw -= tosoil;
        // soil wetness = clip((sm/fc)^beta, 0, 1); sm<=fc invariant so only
        // the upper clamp matters numerically
        const float r   = sm * inv_fc;
        float wet = __expf(beta * __logf(r));
        wet = fminf(wet, 1.0f);
        const float inflow = rain + tosoil;
        const float rech   = inflow * wet;
        sm += inflow - rech;
        const float exc = fmaxf(sm - fc, 0.0f);
        sm -= exc;
        const float ef = fminf(sm * inv_lpfc, 1.0f);
        const float et = fminf(sm, pet * ef);
        sm = fmaxf(sm - et, 1e-5f);
        suz += rech + exc;
        const float perc = fminf(suz, pperc);
        suz -= perc;
        const float q0 = k0 * fmaxf(suz - uzl, 0.0f);
        suz -= q0;
        const float q1 = k1 * suz;
        suz -= q1;
        slz += perc;
        const float q2 = k2 * slz;
        slz -= q2;
        return q0 + q1 + q2;
    };

    // ---- software-pipelined chunked time loop (prefetch chunk t+CH) ----
    float cur[CH][3];
    #pragma unroll
    for (int i = 0; i < CH; i++) {
        const float* p = x + ((size_t)i * G + g) * 3;
        cur[i][0] = p[0]; cur[i][1] = p[1]; cur[i][2] = p[2];
    }

    // warmup phase: t = 0 .. WARMUP-1
    for (int tc = 0; tc < WARMUP; tc += CH) {
        float nxt[CH][3];
        #pragma unroll
        for (int i = 0; i < CH; i++) {
            const float* p = x + ((size_t)(tc + CH + i) * G + g) * 3;
            nxt[i][0] = p[0]; nxt[i][1] = p[1]; nxt[i][2] = p[2];
        }
        #pragma unroll
        for (int i = 0; i < CH; i++)
            (void)step(cur[i][0], cur[i][1], cur[i][2]);
        #pragma unroll
        for (int i = 0; i < CH; i++) {
            cur[i][0] = nxt[i][0]; cur[i][1] = nxt[i][1]; cur[i][2] = nxt[i][2];
        }
    }

    // main phase: t = WARMUP .. TTOT-1, fused 15-tap causal convolution
    float buf[KERNEL_];
    #pragma unroll
    for (int k = 0; k < KERNEL_; k++) buf[k] = 0.0f;

    for (int tc = WARMUP; tc < TTOT; tc += CH) {
        float nxt[CH][3];
        #pragma unroll
        for (int i = 0; i < CH; i++) {
            int tn = tc + CH + i;
            if (tn > TTOT - 1) tn = TTOT - 1;   // clamp (last chunk prefetch)
            const float* p = x + ((size_t)tn * G + g) * 3;
            nxt[i][0] = p[0]; nxt[i][1] = p[1]; nxt[i][2] = p[2];
        }
        #pragma unroll
        for (int i = 0; i < CH; i++) {
            const float q = step(cur[i][0], cur[i][1], cur[i][2]);
            // rolling register window: buf[k] == q[t-k]
            #pragma unroll
            for (int k = KERNEL_ - 1; k > 0; k--) buf[k] = buf[k - 1];
            buf[0] = q;
            float acc = 0.0f;
            #pragma unroll
            for (int k = 0; k < KERNEL_; k++) acc = fmaf(w[k], buf[k], acc);
            out[(size_t)(tc - WARMUP + i) * G + g] = acc;
        }
        #pragma unroll
        for (int i = 0; i < CH; i++) {
            cur[i][0] = nxt[i][0]; cur[i][1] = nxt[i][1]; cur[i][2] = nxt[i][2];
        }
    }
}

extern "C" void kernel_launch(void* const* d_in, const int* in_sizes, int n_in,
                              void* d_out, int out_size, void* d_ws, size_t ws_size,
                              hipStream_t stream) {
    const float* x      = (const float*)d_in[0];   // (2190, G, 3) f32
    const float* params = (const float*)d_in[1];   // (G, 14) f32
    float* out = (float*)d_out;                    // (1825, G, 1) f32
    const int G = in_sizes[1] / 14;
    const int blocks = (G + 63) / 64;
    hbv_fused_kernel<<<blocks, 64, 0, stream>>>(x, params, out, G);
}